// Round 8
// baseline (229.701 us; speedup 1.0000x reference)
//
#include <hip/hip_runtime.h>

#define NN 2048
#define CC 768
#define HH 12
#define SCALE2 0.18033688011112042f   /* 0.125 * log2(e) */
#define NEGB  -3.0e35f
#define THR   12.0f                    /* defer-max threshold, log2 domain */

typedef __attribute__((ext_vector_type(4))) float f32x4;
typedef __attribute__((ext_vector_type(8))) short short8;
typedef __attribute__((ext_vector_type(8))) unsigned short u16x8;

#if __has_builtin(__builtin_amdgcn_exp2f)
#define EXP2(x) __builtin_amdgcn_exp2f(x)
#else
#define EXP2(x) exp2f(x)
#endif

static __device__ __forceinline__ unsigned short f2bf(float f) {
    unsigned u = __float_as_uint(f);
    u += 0x7FFFu + ((u >> 16) & 1u);   // RNE
    return (unsigned short)(u >> 16);
}

static __device__ __forceinline__ f32x4 MFMA(u16x8 a, u16x8 b, f32x4 c) {
    union { u16x8 u; short8 s; } ua, ub;
    ua.u = a; ub.u = b;
    return __builtin_amdgcn_mfma_f32_16x16x32_bf16(ua.s, ub.s, c, 0, 0, 0);
}

static __device__ __forceinline__ void glds16(const void* g, void* l) {
    __builtin_amdgcn_global_load_lds(
        (const __attribute__((address_space(1))) unsigned int*)g,
        (__attribute__((address_space(3))) unsigned int*)l, 16, 0, 0);
}

// ---------------- f32 -> bf16 convert ----------------
__global__ void cvt_f32_bf16(const float* __restrict__ in,
                             unsigned short* __restrict__ out, int n8) {
    int i = blockIdx.x * blockDim.x + threadIdx.x;
    if (i >= n8) return;
    const f32x4* p = (const f32x4*)(in + (size_t)i * 8);
    f32x4 a = p[0], b = p[1];
    u16x8 o;
    o[0] = f2bf(a[0]); o[1] = f2bf(a[1]); o[2] = f2bf(a[2]); o[3] = f2bf(a[3]);
    o[4] = f2bf(b[0]); o[5] = f2bf(b[1]); o[6] = f2bf(b[2]); o[7] = f2bf(b[3]);
    *(u16x8*)(out + (size_t)i * 8) = o;
}

// ---------------- GEMM: C[M][N] = A[MxK] * Bt[NxK]^T ----------------
__launch_bounds__(256)
__global__ void gemm_bt(const unsigned short* __restrict__ A,
                        const unsigned short* __restrict__ Bt,
                        unsigned short* __restrict__ outB,
                        float* __restrict__ outF,
                        const float* __restrict__ bias,
                        int M, int N, int K, int qcols) {
    __shared__ __align__(16) unsigned short As[128][64];
    __shared__ __align__(16) unsigned short Bs[128][64];
    int tid = threadIdx.x, lane = tid & 63, w = tid >> 6;
    int wm = w >> 1, wn = w & 1;
    int li = lane & 15, g = lane >> 4;
    int bn = blockIdx.x, bm = blockIdx.y;

    f32x4 acc[4][4] = {};

    int lrow = lane >> 3, lsl = lane & 7;
    int xcol = (lsl ^ (lrow & 7)) * 8;          // pre-swizzled source column
    const unsigned short* Ag = A  + (size_t)(bm * 128 + w * 32 + lrow) * K + xcol;
    const unsigned short* Bg = Bt + (size_t)(bn * 128 + w * 32 + lrow) * K + xcol;

    for (int k0 = 0; k0 < K; k0 += 64) {
        __syncthreads();
#pragma unroll
        for (int i = 0; i < 4; ++i) {
            glds16(Ag + (size_t)(i * 8) * K + k0, &As[w * 32 + i * 8][0]);
            glds16(Bg + (size_t)(i * 8) * K + k0, &Bs[w * 32 + i * 8][0]);
        }
        __syncthreads();
#pragma unroll
        for (int kk = 0; kk < 2; ++kk) {
            u16x8 af[4], bf[4];
#pragma unroll
            for (int mi = 0; mi < 4; ++mi)
                af[mi] = *(const u16x8*)&As[wm * 64 + mi * 16 + li][((4 * kk + g) ^ (li & 7)) * 8];
#pragma unroll
            for (int ni = 0; ni < 4; ++ni)
                bf[ni] = *(const u16x8*)&Bs[wn * 64 + ni * 16 + li][((4 * kk + g) ^ (li & 7)) * 8];
            __builtin_amdgcn_s_setprio(1);
#pragma unroll
            for (int mi = 0; mi < 4; ++mi)
#pragma unroll
                for (int ni = 0; ni < 4; ++ni)
                    acc[mi][ni] = MFMA(af[mi], bf[ni], acc[mi][ni]);
            __builtin_amdgcn_s_setprio(0);
        }
    }

#pragma unroll
    for (int mi = 0; mi < 4; ++mi) {
#pragma unroll
        for (int ni = 0; ni < 4; ++ni) {
#pragma unroll
            for (int r = 0; r < 4; ++r) {
                int row = bm * 128 + wm * 64 + mi * 16 + g * 4 + r;
                int col = bn * 128 + wn * 64 + ni * 16 + li;
                float v = acc[mi][ni][r];
                if (outB) {
                    if (col < qcols) v *= SCALE2;
                    outB[(size_t)row * N + col] = f2bf(v);
                } else {
                    outF[(size_t)row * N + col] = v + bias[col];
                }
            }
        }
    }
}

// ---------------- masked flash attention ----------------
// Wave quadrant decomposition: each of 4 waves owns (q-half 32, j-half 32)
// of the 64q x 64j block-iteration -> K/V/pen LDS fragment reads halve
// (shared across its 2 q-tiles), MFMA count unchanged.  Per-wave independent
// online softmax over its j-half; 2-way flash merge in the epilogue via LDS.
// K glds-staged XOR-swizzled; V reg-staged -> packed LDS (one iter ahead).
// Dropped query rows: zeroed Q + suppressed penalties -> uniform softmax.
__launch_bounds__(256, 3)
__global__ void attn_kernel(const unsigned short* __restrict__ qkv,
                            const int* __restrict__ mask,
                            unsigned short* __restrict__ hout) {
    __shared__ __align__(16) unsigned short Ks[2][64][64];
    __shared__ __align__(16) unsigned int   Vp[2][64][32];
    __shared__ __align__(16) float pen[NN];

    int tid = threadIdx.x;
    int lane = tid & 63;
    int w = tid >> 6;
    int li = lane & 15, g = lane >> 4;
    int qh = w >> 1;                   // q-half (0/1)
    int jh = (w & 1) * 32;             // j-half offset within the 64-j tile
    int hh = w & 1;                    // V dword-group half

    // XCD-chunked swizzle: one head's q-blocks stay on one XCD
    int lb = (blockIdx.x & 7) * 96 + (blockIdx.x >> 3);
    int qb = lb & 31;
    int bh = lb >> 5;
    int b = bh / HH, head = bh % HH;
    const int* mb = mask + b * NN;

    {   // penalty table: pen[j] = keep ? 0 : NEGB   (256 thr x 8)
        int i = tid * 8;
        union { int4 v; int a[4]; } m0, m1;
        m0.v = *(const int4*)&mb[i];
        m1.v = *(const int4*)&mb[i + 4];
        f32x4 p0, p1;
#pragma unroll
        for (int r = 0; r < 4; ++r) {
            p0[r] = m0.a[r] ? 0.f : NEGB;
            p1[r] = m1.a[r] ? 0.f : NEGB;
        }
        *(f32x4*)&pen[i] = p0;
        *(f32x4*)&pen[i + 4] = p1;
    }

    const unsigned short* qbase = qkv + (size_t)(b * NN) * 2304;

    // Q fragments: 2 q-tiles per wave (k-mapping: d = 32*kk + 8*g + e)
    u16x8 qf[2][2];
    float pm[2];
#pragma unroll
    for (int qt = 0; qt < 2; ++qt) {
        int qrow = qb * 64 + qh * 32 + qt * 16 + li;
        const unsigned short* qp = qbase + (size_t)qrow * 2304 + head * 64;
        u16x8 a0 = *(const u16x8*)(qp + g * 8);
        u16x8 a1 = *(const u16x8*)(qp + 32 + g * 8);
        bool rk = mb[qrow] != 0;
        pm[qt] = rk ? 1.f : 0.f;
        if (!rk) { a0 = (u16x8)0; a1 = (u16x8)0; }   // dropped query -> logits 0
        qf[qt][0] = a0; qf[qt][1] = a1;
    }

    // K glds lane constants (pre-swizzled source column)
    int xslot = ((lane & 7) ^ ((lane >> 3) & 7)) * 8;
    const unsigned short* kg = qbase + CC + head * 64 + xslot
                               + (size_t)(w * 16 + (lane >> 3)) * 2304;

    // V staging lane constants (thread covers jpair 2*vm, 2*vm+1)
    int vm = tid >> 3;                 // 0..31
    int vkc = (tid & 7) * 8;           // d base
    int vcol = (vm & 16) | ((vm & 6) << 1) | ((vm & 8) >> 2) | (vm & 1);
    int vslot = vcol >> 2, vsub = vcol & 3;
    const unsigned short* vg = qbase + 2 * CC + head * 64 + vkc;

    u16x8 va, vb;
    auto stageK = [&](int buf, int kb) {
        glds16(kg + (size_t)kb * 2304,       &Ks[buf][w * 16][0]);
        glds16(kg + (size_t)(kb + 8) * 2304, &Ks[buf][w * 16 + 8][0]);
    };
    auto loadV = [&](int kb) {
        va = *(const u16x8*)(vg + (size_t)(kb + 2 * vm) * 2304);
        vb = *(const u16x8*)(vg + (size_t)(kb + 2 * vm + 1) * 2304);
    };
    auto writeV = [&](int buf) {
        union { u16x8 v; unsigned u[4]; } ua, ub;
        ua.v = va; ub.v = vb;
        unsigned* vp = &Vp[buf][0][0];
#pragma unroll
        for (int e = 0; e < 8; ++e) {
            int dd = (e + (tid & 7)) & 7;          // lane-staggered write order
            unsigned dw = __builtin_amdgcn_perm(ub.u[dd >> 1], ua.u[dd >> 1],
                                                (dd & 1) ? 0x07060302u : 0x05040100u);
            int d0 = vkc + dd;
            vp[d0 * 32 + ((vslot ^ (d0 & 7)) << 2) + vsub] = dw;
        }
    };

    // prologue: tile0 staged+written, tile1 in regs
    stageK(0, 0);
    loadV(0);
    writeV(0);
    loadV(64);

    float m_st[2] = {-1e30f, -1e30f};
    float l_part[2] = {0.f, 0.f};      // per-lane partials; reduced at end
    f32x4 acc[2][4] = {};

    for (int it = 0; it < 32; ++it) {
        __syncthreads();
        int cur = it & 1, nx = cur ^ 1;
        if (it < 31) { writeV(nx); stageK(nx, (it + 1) * 64); }
        if (it < 30) loadV((it + 2) * 64);

        // ---- penalties as MFMA C-init (wave's own j-half) ----
        const float* pp = &pen[it * 64 + jh];
        f32x4 ci[2][2];
#pragma unroll
        for (int t = 0; t < 2; ++t) {
            f32x4 p4 = *(const f32x4*)&pp[t * 16 + g * 4];
            ci[0][t] = p4 * pm[0];
            ci[1][t] = p4 * pm[1];
        }

        // ---- S^T: K * Q^T (K frags shared across the wave's 2 q-tiles) ----
        f32x4 st[2][2];
        __builtin_amdgcn_s_setprio(1);
#pragma unroll
        for (int t = 0; t < 2; ++t) {
            const unsigned short* kr = &Ks[cur][jh + t * 16 + li][0];
            u16x8 k0 = *(const u16x8*)(kr + ((g ^ (li & 7)) * 8));
            u16x8 k1 = *(const u16x8*)(kr + (((4 + g) ^ (li & 7)) * 8));
            f32x4 z0 = ci[0][t], z1 = ci[1][t];
            z0 = MFMA(k0, qf[0][0], z0);
            z1 = MFMA(k0, qf[1][0], z1);
            z0 = MFMA(k1, qf[0][1], z0);
            z1 = MFMA(k1, qf[1][1], z1);
            st[0][t] = z0; st[1][t] = z1;
        }
        __builtin_amdgcn_s_setprio(0);

        // ---- per-wave online softmax (base-2), defer-max ----
        float lmax[2];
#pragma unroll
        for (int qt = 0; qt < 2; ++qt) {
            f32x4 a = st[qt][0], c = st[qt][1];
            lmax[qt] = fmaxf(fmaxf(fmaxf(a[0], a[1]), fmaxf(a[2], a[3])),
                             fmaxf(fmaxf(c[0], c[1]), fmaxf(c[2], c[3])));
        }
        bool trig = (lmax[0] > m_st[0] + THR) || (lmax[1] > m_st[1] + THR);
        if (__any(trig)) {
#pragma unroll
            for (int qt = 0; qt < 2; ++qt) {
                float tm = lmax[qt];
                tm = fmaxf(tm, __shfl_xor(tm, 16));
                tm = fmaxf(tm, __shfl_xor(tm, 32));
                float mnew = fmaxf(m_st[qt], tm);
                float alpha = EXP2(m_st[qt] - mnew);
                float ar[4];
#pragma unroll
                for (int r = 0; r < 4; ++r) ar[r] = __shfl(alpha, g * 4 + r);
#pragma unroll
                for (int dt = 0; dt < 4; ++dt)
#pragma unroll
                    for (int r = 0; r < 4; ++r) acc[qt][dt][r] *= ar[r];
                l_part[qt] *= alpha;
                m_st[qt] = mnew;
            }
        }
        union { unsigned u[4]; u16x8 v8; } pu[2];
#pragma unroll
        for (int qt = 0; qt < 2; ++qt)
#pragma unroll
            for (int t = 0; t < 2; ++t) {
                f32x4 e4;
#pragma unroll
                for (int r = 0; r < 4; ++r) {
                    e4[r] = EXP2(st[qt][t][r] - m_st[qt]);
                    l_part[qt] += e4[r];
                }
                pu[qt].u[t * 2]     = __builtin_amdgcn_perm(__float_as_uint(e4[1]),
                                                            __float_as_uint(e4[0]), 0x07060302u);
                pu[qt].u[t * 2 + 1] = __builtin_amdgcn_perm(__float_as_uint(e4[3]),
                                                            __float_as_uint(e4[2]), 0x07060302u);
            }

        // ---- PV on the wave's j-half (V frags shared across q-tiles) ----
        __builtin_amdgcn_s_setprio(1);
#pragma unroll
        for (int dt = 0; dt < 4; ++dt) {
            const unsigned* vr = &Vp[cur][dt * 16 + li][0];
            u16x8 vf = *(const u16x8*)(vr + (((4 * hh + g) ^ (li & 7)) << 2));
            acc[0][dt] = MFMA(pu[0].v8, vf, acc[0][dt]);
            acc[1][dt] = MFMA(pu[1].v8, vf, acc[1][dt]);
        }
        __builtin_amdgcn_s_setprio(0);
    }

    // ---- epilogue: 2-way flash merge of j-halves, normalize, store ----
    float l_red[2];
#pragma unroll
    for (int qt = 0; qt < 2; ++qt) {
        float l = l_part[qt];
        l += __shfl_xor(l, 16);
        l += __shfl_xor(l, 32);
        l_red[qt] = l;
    }

    float* mrg = (float*)&Ks[0][0][0];   // [2][32][64] partial acc
    float* mlb = (float*)&Vp[0][0][0];   // [2][{m,l}][32]
    __syncthreads();
    if (w & 1) {                          // odd waves publish partials
#pragma unroll
        for (int qt = 0; qt < 2; ++qt) {
#pragma unroll
            for (int dt = 0; dt < 4; ++dt)
#pragma unroll
                for (int r = 0; r < 4; ++r)
                    mrg[qh * 2048 + (qt * 16 + g * 4 + r) * 64 + dt * 16 + li] =
                        acc[qt][dt][r];
            if (g == 0) {
                mlb[qh * 64 + qt * 16 + li] = m_st[qt];
                mlb[qh * 64 + 32 + qt * 16 + li] = l_red[qt];
            }
        }
    }
    __syncthreads();
    if (!(w & 1)) {                       // even waves merge + write out
#pragma unroll
        for (int qt = 0; qt < 2; ++qt) {
            float m_p = mlb[qh * 64 + qt * 16 + li];
            float l_p = mlb[qh * 64 + 32 + qt * 16 + li];
            float ms = fmaxf(m_st[qt], m_p);
            float ae = EXP2(m_st[qt] - ms);
            float ap = EXP2(m_p - ms);
            float linv = 1.0f / (l_red[qt] * ae + l_p * ap);
            float fe = ae * linv, fp = ap * linv;
            float fer[4], fpr[4];
#pragma unroll
            for (int r = 0; r < 4; ++r) {
                fer[r] = __shfl(fe, g * 4 + r);
                fpr[r] = __shfl(fp, g * 4 + r);
            }
            size_t obase = ((size_t)(b * NN + qb * 64 + qh * 32 + qt * 16)) * CC + head * 64;
#pragma unroll
            for (int dt = 0; dt < 4; ++dt)
#pragma unroll
                for (int r = 0; r < 4; ++r) {
                    float vpart = mrg[qh * 2048 + (qt * 16 + g * 4 + r) * 64 + dt * 16 + li];
                    hout[obase + (size_t)(g * 4 + r) * CC + dt * 16 + li] =
                        f2bf(acc[qt][dt][r] * fer[r] + vpart * fpr[r]);
                }
        }
    }
}

extern "C" void kernel_launch(void* const* d_in, const int* in_sizes, int n_in,
                              void* d_out, int out_size, void* d_ws, size_t ws_size,
                              hipStream_t stream) {
    const float* x     = (const float*)d_in[0];
    const int*   mask  = (const int*)d_in[1];
    const float* wqkv  = (const float*)d_in[2];
    const float* wproj = (const float*)d_in[3];
    const float* bproj = (const float*)d_in[4];
    float* out = (float*)d_out;

    unsigned short* x_bf     = (unsigned short*)d_ws;          // 4096*768
    unsigned short* wqkv_bf  = x_bf + 3145728;                 // 2304*768
    unsigned short* wproj_bf = wqkv_bf + 1769472;              // 768*768
    unsigned short* qkv_bf   = wproj_bf + 589824;              // 4096*2304
    unsigned short* h_bf     = qkv_bf + 9437184;               // 4096*768

    cvt_f32_bf16<<<1536, 256, 0, stream>>>(x, x_bf, 393216);
    cvt_f32_bf16<<<864, 256, 0, stream>>>(wqkv, wqkv_bf, 221184);
    cvt_f32_bf16<<<288, 256, 0, stream>>>(wproj, wproj_bf, 73728);

    // qkv = x @ w_qkv^T -> bf16 (Q columns pre-scaled by SCALE*log2e)
    gemm_bt<<<dim3(18, 32), 256, 0, stream>>>(x_bf, wqkv_bf, qkv_bf, nullptr,
                                              nullptr, 4096, 2304, 768, 768);
    // masked flash attention -> h (B,N,C) bf16
    attn_kernel<<<768, 256, 0, stream>>>(qkv_bf, mask, h_bf);
    // out = h @ w_proj^T + b -> f32
    gemm_bt<<<dim3(6, 32), 256, 0, stream>>>(h_bf, wproj_bf, nullptr, out,
                                             bproj, 4096, 768, 768, 0);
}